// Round 13
// baseline (197.561 us; speedup 1.0000x reference)
//
#include <hip/hip_runtime.h>
#include <hip/hip_fp16.h>

#define NN 100000
#define NE 1600000

typedef short s8v __attribute__((ext_vector_type(8)));          // 8 bf16 = 4 VGPRs
typedef float f4 __attribute__((ext_vector_type(4)));

// ---------- dtype helpers ----------
__device__ __forceinline__ unsigned short f2b(float f) {        // fp32 -> bf16 RNE
    unsigned int u = __float_as_uint(f);
    return (unsigned short)((u + 0x7fffu + ((u >> 16) & 1u)) >> 16);
}
__device__ __forceinline__ unsigned int pack2(float a, float b) {
    return (unsigned int)f2b(a) | ((unsigned int)f2b(b) << 16);
}

// ---------- workspace: pk@0 [100000 __half2 = 400000 B] (x=msg sum, y=count) ----------
// No staged weights: each block builds its MFMA A-fragments inline from the raw
// fp32 weight arrays (18 KB hot region, L2-resident). Graph = memset + 2 kernels.
// Floats fp32, edge_index int32 (proven R8); sniff per-wave via __ballot.

// ---------- edge kernel: phi as MFMA, 1-deep pipeline, inline weights ----------
__global__ __launch_bounds__(256) void edge_mfma(
    const float* __restrict__ x, const float* __restrict__ pos,
    const int* __restrict__ ei, __half2* __restrict__ pk,
    const float* __restrict__ pW0, const float* __restrict__ pb0,
    const float* __restrict__ pW1, const float* __restrict__ pb1,
    const float* __restrict__ pW2, const float* __restrict__ pb2)
{
    const int lane = threadIdx.x & 63;
    const int c    = lane & 15;
    const int quad = lane >> 4;

    // ---- sniff edge-index width: int64 <=> all 64 odd words zero ----
    unsigned long long mball = __ballot(ei[2 * lane + 1] == 0);
    const bool fidx = (mball == ~0ULL);     // wave-uniform

    // ---- inline A-fragment build (bias folded at k=18) ----
    s8v wA0[4], wA1[8];
#pragma unroll
    for (int t = 0; t < 4; t++) {
        float v[8];
#pragma unroll
        for (int j = 0; j < 8; j++) {
            int k = quad * 8 + j;
            int n = t * 16 + c;
            v[j] = (k < 18) ? pW0[k * 64 + n] : ((k == 18) ? pb0[n] : 0.0f);
        }
        uint4 q; q.x = pack2(v[0], v[1]); q.y = pack2(v[2], v[3]);
        q.z = pack2(v[4], v[5]); q.w = pack2(v[6], v[7]);
        wA0[t] = __builtin_bit_cast(s8v, q);
    }
#pragma unroll
    for (int f = 0; f < 8; f++) {
        int kt = f & 1, t2 = f >> 1;
        float v[8];
#pragma unroll
        for (int j = 0; j < 8; j++) {
            int k = kt * 32 + quad * 8 + j;
            int n = t2 * 16 + c;
            v[j] = pW1[k * 64 + n];
        }
        uint4 q; q.x = pack2(v[0], v[1]); q.y = pack2(v[2], v[3]);
        q.z = pack2(v[4], v[5]); q.w = pack2(v[6], v[7]);
        wA1[f] = __builtin_bit_cast(s8v, q);
    }
    f4 b1v[4], w2v[4];
#pragma unroll
    for (int t2 = 0; t2 < 4; t2++) {
        b1v[t2] = *(const f4*)(pb1 + t2 * 16 + quad * 4);
        w2v[t2] = *(const f4*)(pW2 + t2 * 16 + quad * 4);
    }
    const float phib2 = pb2[0];

    const float2* pf = (const float2*)pos;

    const int NT    = NE / 16;
    const int gw    = blockIdx.x * 4 + (threadIdx.x >> 6);
    const int nwave = gridDim.x * 4;

    // ---- prologue: first tile's indices + gather ----
    int eg0 = gw * 16 + c;
    int src, dst;
    if (fidx) { src = ei[2 * eg0]; dst = ei[2 * (NE + eg0)]; }
    else      { src = ei[eg0];     dst = ei[NE + eg0]; }
    if ((unsigned)src >= (unsigned)NN) src = 0;
    if ((unsigned)dst >= (unsigned)NN) dst = 0;
    int sel = (quad == 1) ? src : dst;
    f4 xa = *(const f4*)(x + sel * 8);
    f4 xb = *(const f4*)(x + sel * 8 + 4);
    float2 ps = pf[src], pd = pf[dst];

    for (int tile = gw; tile < NT; tile += nwave) {
        const int  ntile     = tile + nwave;
        const bool have_next = ntile < NT;     // wave-uniform

        float g0 = xa[0], g1 = xa[1], g2 = xa[2], g3 = xa[3];
        float g4 = xb[0], g5 = xb[1], g6 = xb[2], g7 = xb[3];
        if (quad == 2) {
            g0 = ps.x - pd.x; g1 = ps.y - pd.y; g2 = 1.0f;
            g3 = 0.f; g4 = 0.f; g5 = 0.f; g6 = 0.f; g7 = 0.f;
        } else if (quad == 3) {
            g0 = g1 = g2 = g3 = g4 = g5 = g6 = g7 = 0.f;
        }
        uint4 bq;
        bq.x = pack2(g0, g1); bq.y = pack2(g2, g3);
        bq.z = pack2(g4, g5); bq.w = pack2(g6, g7);
        s8v bfrag = __builtin_bit_cast(s8v, bq);

        // ---- next tile's ei loads (hide under layer-1) ----
        int nsrc = 0, ndst = 0;
        if (have_next) {
            int neg = ntile * 16 + c;
            if (fidx) { nsrc = ei[2 * neg]; ndst = ei[2 * (NE + neg)]; }
            else      { nsrc = ei[neg];     ndst = ei[NE + neg]; }
        }

        f4 z = {0.f, 0.f, 0.f, 0.f};
        f4 C1[4];
#pragma unroll
        for (int t = 0; t < 4; t++)
            C1[t] = __builtin_amdgcn_mfma_f32_16x16x32_bf16(wA0[t], bfrag, z, 0, 0, 0);

        unsigned int p00 = pack2(fmaxf(C1[0][0], 0.f), fmaxf(C1[0][1], 0.f));
        unsigned int p01 = pack2(fmaxf(C1[0][2], 0.f), fmaxf(C1[0][3], 0.f));
        unsigned int p10 = pack2(fmaxf(C1[1][0], 0.f), fmaxf(C1[1][1], 0.f));
        unsigned int p11 = pack2(fmaxf(C1[1][2], 0.f), fmaxf(C1[1][3], 0.f));
        unsigned int p20 = pack2(fmaxf(C1[2][0], 0.f), fmaxf(C1[2][1], 0.f));
        unsigned int p21 = pack2(fmaxf(C1[2][2], 0.f), fmaxf(C1[2][3], 0.f));
        unsigned int p30 = pack2(fmaxf(C1[3][0], 0.f), fmaxf(C1[3][1], 0.f));
        unsigned int p31 = pack2(fmaxf(C1[3][2], 0.f), fmaxf(C1[3][3], 0.f));

        int s0 = ((quad & 1) << 5) + c;
        int s1 = s0 + 16;
        unsigned int A00 = __shfl(p00, s0, 64), A01 = __shfl(p01, s0, 64);
        unsigned int A10 = __shfl(p10, s0, 64), A11 = __shfl(p11, s0, 64);
        unsigned int A20 = __shfl(p20, s0, 64), A21 = __shfl(p21, s0, 64);
        unsigned int A30 = __shfl(p30, s0, 64), A31 = __shfl(p31, s0, 64);
        unsigned int B00 = __shfl(p00, s1, 64), B01 = __shfl(p01, s1, 64);
        unsigned int B10 = __shfl(p10, s1, 64), B11 = __shfl(p11, s1, 64);
        unsigned int B20 = __shfl(p20, s1, 64), B21 = __shfl(p21, s1, 64);
        unsigned int B30 = __shfl(p30, s1, 64), B31 = __shfl(p31, s1, 64);
        bool hi = (quad >> 1) & 1;
        uint4 q0, q1;
        q0.x = hi ? A10 : A00;  q0.y = hi ? A11 : A01;
        q0.z = hi ? B10 : B00;  q0.w = hi ? B11 : B01;
        q1.x = hi ? A30 : A20;  q1.y = hi ? A31 : A21;
        q1.z = hi ? B30 : B20;  q1.w = hi ? B31 : B21;
        s8v b2f0 = __builtin_bit_cast(s8v, q0);
        s8v b2f1 = __builtin_bit_cast(s8v, q1);

        // ---- next tile's x/pos gather (hide under layer-2) ----
        f4 nxa = xa, nxb = xb;
        float2 nps = ps, npd = pd;
        if (have_next) {
            if ((unsigned)nsrc >= (unsigned)NN) nsrc = 0;
            if ((unsigned)ndst >= (unsigned)NN) ndst = 0;
            int nsel = (quad == 1) ? nsrc : ndst;
            nxa = *(const f4*)(x + nsel * 8);
            nxb = *(const f4*)(x + nsel * 8 + 4);
            nps = pf[nsrc]; npd = pf[ndst];
        }

        f4 C2[4];
#pragma unroll
        for (int t2 = 0; t2 < 4; t2++) {
            C2[t2] = __builtin_amdgcn_mfma_f32_16x16x32_bf16(wA1[t2 * 2 + 0], b2f0, z, 0, 0, 0);
            C2[t2] = __builtin_amdgcn_mfma_f32_16x16x32_bf16(wA1[t2 * 2 + 1], b2f1, C2[t2], 0, 0, 0);
        }

        float pm = 0.f;
#pragma unroll
        for (int t2 = 0; t2 < 4; t2++) {
#pragma unroll
            for (int r = 0; r < 4; r++)
                pm = fmaf(fmaxf(C2[t2][r] + b1v[t2][r], 0.f), w2v[t2][r], pm);
        }
        pm += __shfl_xor(pm, 16, 64);
        pm += __shfl_xor(pm, 32, 64);
        float msg = pm + phib2;

        if (quad == 0)      // one packed atomic per edge: (msg, 1.0)
            unsafeAtomicAdd(pk + dst, __halves2half2(__float2half(msg), __float2half(1.0f)));

        src = nsrc; dst = ndst;
        xa = nxa; xb = nxb; ps = nps; pd = npd;
    }
}

// ---------- node kernel: gamma as MFMA, inline weights, no atomics ----------
__global__ __launch_bounds__(256) void node_mfma(
    const float* __restrict__ x, const __half2* __restrict__ pk,
    float* __restrict__ out,
    const float* __restrict__ gW0, const float* __restrict__ gb0,
    const float* __restrict__ gW1, const float* __restrict__ gb1,
    const float* __restrict__ gW2, const float* __restrict__ gb2)
{
    const int lane = threadIdx.x & 63;
    const int c    = lane & 15;
    const int quad = lane >> 4;

    // ---- inline A-fragment build (bias folded at k=9) ----
    s8v wA0[4], wA1[8];
#pragma unroll
    for (int t = 0; t < 4; t++) {
        float v[8];
#pragma unroll
        for (int j = 0; j < 8; j++) {
            int k = quad * 8 + j;
            int n = t * 16 + c;
            v[j] = (k < 9) ? gW0[k * 64 + n] : ((k == 9) ? gb0[n] : 0.0f);
        }
        uint4 q; q.x = pack2(v[0], v[1]); q.y = pack2(v[2], v[3]);
        q.z = pack2(v[4], v[5]); q.w = pack2(v[6], v[7]);
        wA0[t] = __builtin_bit_cast(s8v, q);
    }
#pragma unroll
    for (int f = 0; f < 8; f++) {
        int kt = f & 1, t2 = f >> 1;
        float v[8];
#pragma unroll
        for (int j = 0; j < 8; j++) {
            int k = kt * 32 + quad * 8 + j;
            int n = t2 * 16 + c;
            v[j] = gW1[k * 64 + n];
        }
        uint4 q; q.x = pack2(v[0], v[1]); q.y = pack2(v[2], v[3]);
        q.z = pack2(v[4], v[5]); q.w = pack2(v[6], v[7]);
        wA1[f] = __builtin_bit_cast(s8v, q);
    }
    f4 b1v[4], w2v[4];
#pragma unroll
    for (int t2 = 0; t2 < 4; t2++) {
        b1v[t2] = *(const f4*)(gb1 + t2 * 16 + quad * 4);
        w2v[t2] = *(const f4*)(gW2 + t2 * 16 + quad * 4);
    }
    const float gamb2 = gb2[0];

    const int gw    = blockIdx.x * 4 + (threadIdx.x >> 6);
    const int nwave = gridDim.x * 4;

    for (int tile = gw; tile < NN / 16 + 1; tile += nwave) {   // 6251 tiles (last partial)
        int n = tile * 16 + c;
        if (n >= NN) n = NN - 1;

        f4 xa = *(const f4*)(x + n * 8);
        f4 xb = *(const f4*)(x + n * 8 + 4);
        __half2 pc = pk[n];
        float aggv = __half2float(pc.x) / fmaxf(__half2float(pc.y), 1.0f);

        float g0 = xa[0], g1 = xa[1], g2 = xa[2], g3 = xa[3];
        float g4 = xb[0], g5 = xb[1], g6 = xb[2], g7 = xb[3];
        if (quad == 1) {
            g0 = aggv; g1 = 1.0f;           // k=8: agg, k=9: bias row
            g2 = 0.f; g3 = 0.f; g4 = 0.f; g5 = 0.f; g6 = 0.f; g7 = 0.f;
        } else if (quad >= 2) {
            g0 = g1 = g2 = g3 = g4 = g5 = g6 = g7 = 0.f;
        }
        uint4 bq;
        bq.x = pack2(g0, g1); bq.y = pack2(g2, g3);
        bq.z = pack2(g4, g5); bq.w = pack2(g6, g7);
        s8v bfrag = __builtin_bit_cast(s8v, bq);

        f4 z = {0.f, 0.f, 0.f, 0.f};
        f4 C1[4];
#pragma unroll
        for (int t = 0; t < 4; t++)
            C1[t] = __builtin_amdgcn_mfma_f32_16x16x32_bf16(wA0[t], bfrag, z, 0, 0, 0);

        unsigned int p00 = pack2(fmaxf(C1[0][0], 0.f), fmaxf(C1[0][1], 0.f));
        unsigned int p01 = pack2(fmaxf(C1[0][2], 0.f), fmaxf(C1[0][3], 0.f));
        unsigned int p10 = pack2(fmaxf(C1[1][0], 0.f), fmaxf(C1[1][1], 0.f));
        unsigned int p11 = pack2(fmaxf(C1[1][2], 0.f), fmaxf(C1[1][3], 0.f));
        unsigned int p20 = pack2(fmaxf(C1[2][0], 0.f), fmaxf(C1[2][1], 0.f));
        unsigned int p21 = pack2(fmaxf(C1[2][2], 0.f), fmaxf(C1[2][3], 0.f));
        unsigned int p30 = pack2(fmaxf(C1[3][0], 0.f), fmaxf(C1[3][1], 0.f));
        unsigned int p31 = pack2(fmaxf(C1[3][2], 0.f), fmaxf(C1[3][3], 0.f));

        int s0 = ((quad & 1) << 5) + c;
        int s1 = s0 + 16;
        unsigned int A00 = __shfl(p00, s0, 64), A01 = __shfl(p01, s0, 64);
        unsigned int A10 = __shfl(p10, s0, 64), A11 = __shfl(p11, s0, 64);
        unsigned int A20 = __shfl(p20, s0, 64), A21 = __shfl(p21, s0, 64);
        unsigned int A30 = __shfl(p30, s0, 64), A31 = __shfl(p31, s0, 64);
        unsigned int B00 = __shfl(p00, s1, 64), B01 = __shfl(p01, s1, 64);
        unsigned int B10 = __shfl(p10, s1, 64), B11 = __shfl(p11, s1, 64);
        unsigned int B20 = __shfl(p20, s1, 64), B21 = __shfl(p21, s1, 64);
        unsigned int B30 = __shfl(p30, s1, 64), B31 = __shfl(p31, s1, 64);
        bool hi = (quad >> 1) & 1;
        uint4 q0, q1;
        q0.x = hi ? A10 : A00;  q0.y = hi ? A11 : A01;
        q0.z = hi ? B10 : B00;  q0.w = hi ? B11 : B01;
        q1.x = hi ? A30 : A20;  q1.y = hi ? A31 : A21;
        q1.z = hi ? B30 : B20;  q1.w = hi ? B31 : B21;
        s8v b2f0 = __builtin_bit_cast(s8v, q0);
        s8v b2f1 = __builtin_bit_cast(s8v, q1);

        f4 C2[4];
#pragma unroll
        for (int t2 = 0; t2 < 4; t2++) {
            C2[t2] = __builtin_amdgcn_mfma_f32_16x16x32_bf16(wA1[t2 * 2 + 0], b2f0, z, 0, 0, 0);
            C2[t2] = __builtin_amdgcn_mfma_f32_16x16x32_bf16(wA1[t2 * 2 + 1], b2f1, C2[t2], 0, 0, 0);
        }

        float pm = 0.f;
#pragma unroll
        for (int t2 = 0; t2 < 4; t2++) {
#pragma unroll
            for (int r = 0; r < 4; r++)
                pm = fmaf(fmaxf(C2[t2][r] + b1v[t2][r], 0.f), w2v[t2][r], pm);
        }
        pm += __shfl_xor(pm, 16, 64);
        pm += __shfl_xor(pm, 32, 64);

        int nw = tile * 16 + c;
        if (quad == 0 && nw < NN)
            out[nw] = xb[3] + pm + gamb2;   // residual on last input channel
    }
}

extern "C" void kernel_launch(void* const* d_in, const int* in_sizes, int n_in,
                              void* d_out, int out_size, void* d_ws, size_t ws_size,
                              hipStream_t stream) {
    const float* x   = (const float*)d_in[0];
    const float* pos = (const float*)d_in[1];
    const int*   ei  = (const int*)d_in[2];   // int32 (harness converts integers)

    __half2* pk = (__half2*)d_ws;             // 100000 __half2 accumulators

    hipMemsetAsync(d_ws, 0, NN * sizeof(__half2), stream);   // native graph memset node

    edge_mfma<<<2048, 256, 0, stream>>>(
        x, pos, ei, pk,
        (const float*)d_in[3], (const float*)d_in[4], (const float*)d_in[5],
        (const float*)d_in[6], (const float*)d_in[7], (const float*)d_in[8]);

    node_mfma<<<2048, 256, 0, stream>>>(
        x, pk, (float*)d_out,
        (const float*)d_in[9],  (const float*)d_in[10], (const float*)d_in[11],
        (const float*)d_in[12], (const float*)d_in[13], (const float*)d_in[14]);
}

// Round 14
// 191.420 us; speedup vs baseline: 1.0321x; 1.0321x over previous
//
#include <hip/hip_runtime.h>
#include <hip/hip_fp16.h>

#define NN 100000
#define NE 1600000

typedef short s8v __attribute__((ext_vector_type(8)));          // 8 bf16 = 4 VGPRs
typedef float f4 __attribute__((ext_vector_type(4)));

// ---------- dtype helpers ----------
__device__ __forceinline__ unsigned short f2b(float f) {        // fp32 -> bf16 RNE
    unsigned int u = __float_as_uint(f);
    return (unsigned short)((u + 0x7fffu + ((u >> 16) & 1u)) >> 16);
}
__device__ __forceinline__ unsigned int pack2(float a, float b) {
    return (unsigned int)f2b(a) | ((unsigned int)f2b(b) << 16);
}

// ---------- workspace layout (float index) ----------
// pk@0 [50000 floats = 100000 __half2]  (x = msg sum, y = count; pk_add_f16 atomics)
// phi b1 @204868[64] | phi w2 @204932[64] | phi b2 @204996[1]
// phi fragW0 @205000 (2048 bf16) | phi fragW1 @206024 (4096 bf16)
// flags @208100 (1 int)
// gam fragW0 @208104 (2048 bf16) | gam fragW1 @209128 (4096 bf16)
// gam b1 @211176[64] | gam w2 @211240[64] | gam b2 @211304[1]
// Floats fp32, edge_index int32 (proven R8). One pk_add_f16 atomic per edge.
// R14: staged weights (R12 best), predicated x/pos gathers (quads 2-3 never use
// x, only quad2 uses pos), edge grid 4096.

__global__ __launch_bounds__(256) void prep(
    const float* __restrict__ pW0, const float* __restrict__ pb0,
    const float* __restrict__ pW1, const float* __restrict__ pb1,
    const float* __restrict__ pW2, const float* __restrict__ pb2,
    const float* __restrict__ gW0, const float* __restrict__ gb0,
    const float* __restrict__ gW1, const float* __restrict__ gb1,
    const float* __restrict__ gW2, const float* __restrict__ gb2,
    const int* __restrict__ ei, float* __restrict__ ws)
{
    // ---- zero the pk accumulator (all blocks) ----
    for (int i = blockIdx.x * 256 + threadIdx.x; i < 50000; i += gridDim.x * 256)
        ws[i] = 0.0f;

    // ---- sniff edge-index width (last block only) ----
    if (blockIdx.x == gridDim.x - 1) {
        __shared__ int s_zero;
        if (threadIdx.x == 0) s_zero = 0;
        __syncthreads();
        int zero = 0;
        for (int i = threadIdx.x; i < 1024; i += 256)
            if (ei[2 * i + 1] == 0) zero++;      // int64 high words all zero
        atomicAdd(&s_zero, zero);
        __syncthreads();
        if (threadIdx.x == 0) ((int*)(ws + 208100))[0] = (s_zero > 512) ? 1 : 0;
        return;
    }

    // ---- weight staging ----
    int t = blockIdx.x * 256 + threadIdx.x;
    if (t < 4865) {
        if (t < 64)        ws[204868 + t] = pb1[t];
        else if (t < 128)  ws[204932 + t - 64] = pW2[t - 64];
        else if (t == 128) ws[204996] = pb2[0];
    } else if (t < 7042) {                  // phi fragW0: A-frag of W0^T, bias at k=18
        int fe = t - 4994;
        if (fe >= 0) {
            int tt = fe >> 9, ln = (fe >> 3) & 63, j = fe & 7;
            int k = ((ln >> 4) << 3) + j;
            int n = (tt << 4) + (ln & 15);
            float v = (k < 18) ? pW0[k * 64 + n] : ((k == 18) ? pb0[n] : 0.0f);
            ((unsigned short*)(ws + 205000))[fe] = f2b(v);
        }
    } else if (t < 11138) {                 // phi fragW1: A-frag of W1^T
        int fe = t - 7042;
        int f = fe >> 9, ln = (fe >> 3) & 63, j = fe & 7;
        int kt = f & 1, t2 = f >> 1;
        int k = kt * 32 + ((ln >> 4) << 3) + j;
        int n = (t2 << 4) + (ln & 15);
        ((unsigned short*)(ws + 206024))[fe] = f2b(pW1[k * 64 + n]);
    } else if (t < 13186) {                 // gamma fragW0: bias folded at k=9
        int fe = t - 11138;
        int tt = fe >> 9, ln = (fe >> 3) & 63, j = fe & 7;
        int k = ((ln >> 4) << 3) + j;
        int n = (tt << 4) + (ln & 15);
        float v = (k < 9) ? gW0[k * 64 + n] : ((k == 9) ? gb0[n] : 0.0f);
        ((unsigned short*)(ws + 208104))[fe] = f2b(v);
    } else if (t < 17282) {                 // gamma fragW1
        int fe = t - 13186;
        int f = fe >> 9, ln = (fe >> 3) & 63, j = fe & 7;
        int kt = f & 1, t2 = f >> 1;
        int k = kt * 32 + ((ln >> 4) << 3) + j;
        int n = (t2 << 4) + (ln & 15);
        ((unsigned short*)(ws + 209128))[fe] = f2b(gW1[k * 64 + n]);
    } else if (t < 17346) {
        ws[211176 + t - 17282] = gb1[t - 17282];
    } else if (t < 17410) {
        ws[211240 + t - 17346] = gW2[t - 17346];
    } else if (t == 17410) {
        ws[211304] = gb2[0];
    }
}

// ---------- edge kernel: phi as MFMA, 1-deep pipeline, predicated gathers ----------
__global__ __launch_bounds__(256) void edge_mfma(
    const float* __restrict__ x, const float* __restrict__ pos,
    const int* __restrict__ ei, float* __restrict__ ws,
    const int* __restrict__ flags)
{
    const int lane = threadIdx.x & 63;
    const int c    = lane & 15;
    const int quad = lane >> 4;
    const int fidx = flags[0];

    const unsigned short* fw0 = (const unsigned short*)(ws + 205000);
    const unsigned short* fw1 = (const unsigned short*)(ws + 206024);
    s8v wA0[4], wA1[8];
#pragma unroll
    for (int t = 0; t < 4; t++) wA0[t] = *(const s8v*)(fw0 + (t * 64 + lane) * 8);
#pragma unroll
    for (int f = 0; f < 8; f++) wA1[f] = *(const s8v*)(fw1 + (f * 64 + lane) * 8);

    f4 b1v[4], w2v[4];
    const float* b1p = ws + 204868;
    const float* w2p = ws + 204932;
#pragma unroll
    for (int t2 = 0; t2 < 4; t2++) {
        b1v[t2] = *(const f4*)(b1p + t2 * 16 + quad * 4);
        w2v[t2] = *(const f4*)(w2p + t2 * 16 + quad * 4);
    }
    const float phib2 = ws[204996];

    __half2* pk = (__half2*)ws;
    const float2* pf = (const float2*)pos;

    const int NT    = NE / 16;
    const int gw    = blockIdx.x * 4 + (threadIdx.x >> 6);
    const int nwave = gridDim.x * 4;

    // ---- prologue: first tile's indices + predicated gather ----
    int eg0 = gw * 16 + c;
    int src, dst;
    if (fidx) { src = ei[2 * eg0]; dst = ei[2 * (NE + eg0)]; }
    else      { src = ei[eg0];     dst = ei[NE + eg0]; }
    if ((unsigned)src >= (unsigned)NN) src = 0;
    if ((unsigned)dst >= (unsigned)NN) dst = 0;
    f4 xa = {0.f, 0.f, 0.f, 0.f}, xb = {0.f, 0.f, 0.f, 0.f};
    float2 ps = {0.f, 0.f}, pd = {0.f, 0.f};
    if (quad <= 1) {                       // only quads 0,1 consume x
        int sel = (quad == 1) ? src : dst;
        xa = *(const f4*)(x + sel * 8);
        xb = *(const f4*)(x + sel * 8 + 4);
    } else if (quad == 2) {                // only quad 2 consumes pos
        ps = pf[src]; pd = pf[dst];
    }

    for (int tile = gw; tile < NT; tile += nwave) {
        const int  ntile     = tile + nwave;
        const bool have_next = ntile < NT;     // wave-uniform

        float g0 = xa[0], g1 = xa[1], g2 = xa[2], g3 = xa[3];
        float g4 = xb[0], g5 = xb[1], g6 = xb[2], g7 = xb[3];
        if (quad == 2) {
            g0 = ps.x - pd.x; g1 = ps.y - pd.y; g2 = 1.0f;
            g3 = 0.f; g4 = 0.f; g5 = 0.f; g6 = 0.f; g7 = 0.f;
        }
        uint4 bq;
        bq.x = pack2(g0, g1); bq.y = pack2(g2, g3);
        bq.z = pack2(g4, g5); bq.w = pack2(g6, g7);
        s8v bfrag = __builtin_bit_cast(s8v, bq);

        // ---- next tile's ei loads (hide under layer-1) ----
        int nsrc = 0, ndst = 0;
        if (have_next) {
            int neg = ntile * 16 + c;
            if (fidx) { nsrc = ei[2 * neg]; ndst = ei[2 * (NE + neg)]; }
            else      { nsrc = ei[neg];     ndst = ei[NE + neg]; }
        }

        f4 z = {0.f, 0.f, 0.f, 0.f};
        f4 C1[4];
#pragma unroll
        for (int t = 0; t < 4; t++)
            C1[t] = __builtin_amdgcn_mfma_f32_16x16x32_bf16(wA0[t], bfrag, z, 0, 0, 0);

        unsigned int p00 = pack2(fmaxf(C1[0][0], 0.f), fmaxf(C1[0][1], 0.f));
        unsigned int p01 = pack2(fmaxf(C1[0][2], 0.f), fmaxf(C1[0][3], 0.f));
        unsigned int p10 = pack2(fmaxf(C1[1][0], 0.f), fmaxf(C1[1][1], 0.f));
        unsigned int p11 = pack2(fmaxf(C1[1][2], 0.f), fmaxf(C1[1][3], 0.f));
        unsigned int p20 = pack2(fmaxf(C1[2][0], 0.f), fmaxf(C1[2][1], 0.f));
        unsigned int p21 = pack2(fmaxf(C1[2][2], 0.f), fmaxf(C1[2][3], 0.f));
        unsigned int p30 = pack2(fmaxf(C1[3][0], 0.f), fmaxf(C1[3][1], 0.f));
        unsigned int p31 = pack2(fmaxf(C1[3][2], 0.f), fmaxf(C1[3][3], 0.f));

        int s0 = ((quad & 1) << 5) + c;
        int s1 = s0 + 16;
        unsigned int A00 = __shfl(p00, s0, 64), A01 = __shfl(p01, s0, 64);
        unsigned int A10 = __shfl(p10, s0, 64), A11 = __shfl(p11, s0, 64);
        unsigned int A20 = __shfl(p20, s0, 64), A21 = __shfl(p21, s0, 64);
        unsigned int A30 = __shfl(p30, s0, 64), A31 = __shfl(p31, s0, 64);
        unsigned int B00 = __shfl(p00, s1, 64), B01 = __shfl(p01, s1, 64);
        unsigned int B10 = __shfl(p10, s1, 64), B11 = __shfl(p11, s1, 64);
        unsigned int B20 = __shfl(p20, s1, 64), B21 = __shfl(p21, s1, 64);
        unsigned int B30 = __shfl(p30, s1, 64), B31 = __shfl(p31, s1, 64);
        bool hi = (quad >> 1) & 1;
        uint4 q0, q1;
        q0.x = hi ? A10 : A00;  q0.y = hi ? A11 : A01;
        q0.z = hi ? B10 : B00;  q0.w = hi ? B11 : B01;
        q1.x = hi ? A30 : A20;  q1.y = hi ? A31 : A21;
        q1.z = hi ? B30 : B20;  q1.w = hi ? B31 : B21;
        s8v b2f0 = __builtin_bit_cast(s8v, q0);
        s8v b2f1 = __builtin_bit_cast(s8v, q1);

        // ---- next tile's predicated x/pos gather (hide under layer-2) ----
        f4 nxa = xa, nxb = xb;
        float2 nps = ps, npd = pd;
        if (have_next) {
            if ((unsigned)nsrc >= (unsigned)NN) nsrc = 0;
            if ((unsigned)ndst >= (unsigned)NN) ndst = 0;
            if (quad <= 1) {
                int nsel = (quad == 1) ? nsrc : ndst;
                nxa = *(const f4*)(x + nsel * 8);
                nxb = *(const f4*)(x + nsel * 8 + 4);
            } else if (quad == 2) {
                nps = pf[nsrc]; npd = pf[ndst];
            }
        }

        f4 C2[4];
#pragma unroll
        for (int t2 = 0; t2 < 4; t2++) {
            C2[t2] = __builtin_amdgcn_mfma_f32_16x16x32_bf16(wA1[t2 * 2 + 0], b2f0, z, 0, 0, 0);
            C2[t2] = __builtin_amdgcn_mfma_f32_16x16x32_bf16(wA1[t2 * 2 + 1], b2f1, C2[t2], 0, 0, 0);
        }

        float pm = 0.f;
#pragma unroll
        for (int t2 = 0; t2 < 4; t2++) {
#pragma unroll
            for (int r = 0; r < 4; r++)
                pm = fmaf(fmaxf(C2[t2][r] + b1v[t2][r], 0.f), w2v[t2][r], pm);
        }
        pm += __shfl_xor(pm, 16, 64);
        pm += __shfl_xor(pm, 32, 64);
        float msg = pm + phib2;

        if (quad == 0)      // one packed atomic per edge: (msg, 1.0)
            unsafeAtomicAdd(pk + dst, __halves2half2(__float2half(msg), __float2half(1.0f)));

        src = nsrc; dst = ndst;
        xa = nxa; xb = nxb; ps = nps; pd = npd;
    }
}

// ---------- node kernel: gamma as MFMA, staged weights, no atomics ----------
__global__ __launch_bounds__(256) void node_mfma(
    const float* __restrict__ x, float* __restrict__ ws,
    float* __restrict__ out)
{
    const int lane = threadIdx.x & 63;
    const int c    = lane & 15;
    const int quad = lane >> 4;

    const unsigned short* fw0 = (const unsigned short*)(ws + 208104);
    const unsigned short* fw1 = (const unsigned short*)(ws + 209128);
    s8v wA0[4], wA1[8];
#pragma unroll
    for (int t = 0; t < 4; t++) wA0[t] = *(const s8v*)(fw0 + (t * 64 + lane) * 8);
#pragma unroll
    for (int f = 0; f < 8; f++) wA1[f] = *(const s8v*)(fw1 + (f * 64 + lane) * 8);

    f4 b1v[4], w2v[4];
    const float* b1p = ws + 211176;
    const float* w2p = ws + 211240;
#pragma unroll
    for (int t2 = 0; t2 < 4; t2++) {
        b1v[t2] = *(const f4*)(b1p + t2 * 16 + quad * 4);
        w2v[t2] = *(const f4*)(w2p + t2 * 16 + quad * 4);
    }
    const float gamb2 = ws[211304];

    const __half2* pk = (const __half2*)ws;

    const int gw    = blockIdx.x * 4 + (threadIdx.x >> 6);
    const int nwave = gridDim.x * 4;

    for (int tile = gw; tile < NN / 16 + 1; tile += nwave) {   // 6251 tiles (last partial)
        int n = tile * 16 + c;
        if (n >= NN) n = NN - 1;

        f4 xa = *(const f4*)(x + n * 8);
        f4 xb = *(const f4*)(x + n * 8 + 4);
        __half2 pc = pk[n];
        float aggv = __half2float(pc.x) / fmaxf(__half2float(pc.y), 1.0f);

        float g0 = xa[0], g1 = xa[1], g2 = xa[2], g3 = xa[3];
        float g4 = xb[0], g5 = xb[1], g6 = xb[2], g7 = xb[3];
        if (quad == 1) {
            g0 = aggv; g1 = 1.0f;           // k=8: agg, k=9: bias row
            g2 = 0.f; g3 = 0.f; g4 = 0.f; g5 = 0.f; g6 = 0.f; g7 = 0.f;
        } else if (quad >= 2) {
            g0 = g1 = g2 = g3 = g4 = g5 = g6 = g7 = 0.f;
        }
        uint4 bq;
        bq.x = pack2(g0, g1); bq.y = pack2(g2, g3);
        bq.z = pack2(g4, g5); bq.w = pack2(g6, g7);
        s8v bfrag = __builtin_bit_cast(s8v, bq);

        f4 z = {0.f, 0.f, 0.f, 0.f};
        f4 C1[4];
#pragma unroll
        for (int t = 0; t < 4; t++)
            C1[t] = __builtin_amdgcn_mfma_f32_16x16x32_bf16(wA0[t], bfrag, z, 0, 0, 0);

        unsigned int p00 = pack2(fmaxf(C1[0][0], 0.f), fmaxf(C1[0][1], 0.f));
        unsigned int p01 = pack2(fmaxf(C1[0][2], 0.f), fmaxf(C1[0][3], 0.f));
        unsigned int p10 = pack2(fmaxf(C1[1][0], 0.f), fmaxf(C1[1][1], 0.f));
        unsigned int p11 = pack2(fmaxf(C1[1][2], 0.f), fmaxf(C1[1][3], 0.f));
        unsigned int p20 = pack2(fmaxf(C1[2][0], 0.f), fmaxf(C1[2][1], 0.f));
        unsigned int p21 = pack2(fmaxf(C1[2][2], 0.f), fmaxf(C1[2][3], 0.f));
        unsigned int p30 = pack2(fmaxf(C1[3][0], 0.f), fmaxf(C1[3][1], 0.f));
        unsigned int p31 = pack2(fmaxf(C1[3][2], 0.f), fmaxf(C1[3][3], 0.f));

        int s0 = ((quad & 1) << 5) + c;
        int s1 = s0 + 16;
        unsigned int A00 = __shfl(p00, s0, 64), A01 = __shfl(p01, s0, 64);
        unsigned int A10 = __shfl(p10, s0, 64), A11 = __shfl(p11, s0, 64);
        unsigned int A20 = __shfl(p20, s0, 64), A21 = __shfl(p21, s0, 64);
        unsigned int A30 = __shfl(p30, s0, 64), A31 = __shfl(p31, s0, 64);
        unsigned int B00 = __shfl(p00, s1, 64), B01 = __shfl(p01, s1, 64);
        unsigned int B10 = __shfl(p10, s1, 64), B11 = __shfl(p11, s1, 64);
        unsigned int B20 = __shfl(p20, s1, 64), B21 = __shfl(p21, s1, 64);
        unsigned int B30 = __shfl(p30, s1, 64), B31 = __shfl(p31, s1, 64);
        bool hi = (quad >> 1) & 1;
        uint4 q0, q1;
        q0.x = hi ? A10 : A00;  q0.y = hi ? A11 : A01;
        q0.z = hi ? B10 : B00;  q0.w = hi ? B11 : B01;
        q1.x = hi ? A30 : A20;  q1.y = hi ? A31 : A21;
        q1.z = hi ? B30 : B20;  q1.w = hi ? B31 : B21;
        s8v b2f0 = __builtin_bit_cast(s8v, q0);
        s8v b2f1 = __builtin_bit_cast(s8v, q1);

        f4 C2[4];
#pragma unroll
        for (int t2 = 0; t2 < 4; t2++) {
            C2[t2] = __builtin_amdgcn_mfma_f32_16x16x32_bf16(wA1[t2 * 2 + 0], b2f0, z, 0, 0, 0);
            C2[t2] = __builtin_amdgcn_mfma_f32_16x16x32_bf16(wA1[t2 * 2 + 1], b2f1, C2[t2], 0, 0, 0);
        }

        float pm = 0.f;
#pragma unroll
        for (int t2 = 0; t2 < 4; t2++) {
#pragma unroll
            for (int r = 0; r < 4; r++)
                pm = fmaf(fmaxf(C2[t2][r] + b1v[t2][r], 0.f), w2v[t2][r], pm);
        }
        pm += __shfl_xor(pm, 16, 64);
        pm += __shfl_xor(pm, 32, 64);

        int nw = tile * 16 + c;
        if (quad == 0 && nw < NN)
            out[nw] = xb[3] + pm + gamb2;   // residual on last input channel
    }
}

extern "C" void kernel_launch(void* const* d_in, const int* in_sizes, int n_in,
                              void* d_out, int out_size, void* d_ws, size_t ws_size,
                              hipStream_t stream) {
    const float* x   = (const float*)d_in[0];
    const float* pos = (const float*)d_in[1];
    const int*   ei  = (const int*)d_in[2];   // int32 (harness converts integers)

    float* ws    = (float*)d_ws;
    int*   flags = (int*)(ws + 208100);

    prep<<<70, 256, 0, stream>>>(
        (const float*)d_in[3],  (const float*)d_in[4],  (const float*)d_in[5],
        (const float*)d_in[6],  (const float*)d_in[7],  (const float*)d_in[8],
        (const float*)d_in[9],  (const float*)d_in[10], (const float*)d_in[11],
        (const float*)d_in[12], (const float*)d_in[13], (const float*)d_in[14],
        ei, ws);

    edge_mfma<<<4096, 256, 0, stream>>>(x, pos, ei, ws, flags);

    node_mfma<<<1024, 256, 0, stream>>>(x, ws, (float*)d_out);
}